// Round 9
// baseline (187.211 us; speedup 1.0000x reference)
//
#include <hip/hip_runtime.h>
#include <hip/hip_cooperative_groups.h>
#include <math.h>

namespace cg = cooperative_groups;

// ---------------------------------------------------------------------------
// NeuralNet_62045097558546 on MI355X (gfx950)
// 3x (GEMM+bias+ReLU+cmax -> soft-topk mask) -> GEMM+bias
// GEMMs: bf16 MFMA split precision, C = Ahi*Bhi + Ahi*Blo + Alo*Bhi as one
// bf16 GEMM over K' = 3K. Physical: compact [hi(NTK)|lo(NTK)] 4KB tiles.
//   A'=[hi|hi|lo]: ta = t<NTK ? t : t-NTK
//   B'=[hi|lo|hi]: tb = t<2NTK ? t : t-2NTK
// FRAGMENT-ORDER BLOCKED LAYOUT: panel p (64 rows) -> tile t (32 k') ->
//   slot s = (m>>4)*64 + g*16 + (m&15) (8 shorts: row m, k-chunk g).
//   Fragment load for sub-tile s16 = ONE contiguous 1KB block per 64 lanes.
// K-loop: no LDS/barriers/atomics; compile-time 3-stage register pipeline.
//
// Preferred path: ONE cooperative kernel, 256 blocks (1/CU co-residency is
// always satisfiable) x 256 thr; gemm does 2 col-panels per block. Fallback
// (if coop unsupported / occupancy gate fails): round-7 multi-kernel path.
// ---------------------------------------------------------------------------

typedef __attribute__((ext_vector_type(8))) short short8;
typedef __attribute__((ext_vector_type(4))) float f32x4;

__device__ __forceinline__ unsigned short f2bf(float f) {
  unsigned u = __float_as_uint(f);
  u += 0x7fffu + ((u >> 16) & 1u);
  return (unsigned short)(u >> 16);
}
__device__ __forceinline__ float bf2f(unsigned short s) {
  return __uint_as_float(((unsigned)s) << 16);
}

struct MegaArgs {
  const float *x, *W1, *b1, *W2, *b2, *W3, *b3, *W4, *b4;
  const int* sparse;
  float* out;
  short *Ablk, *B1blk, *B2blk, *B3blk, *Hmblk;
  float *H, *bp, *cmaxA;
};

__device__ __forceinline__ void cvt_store16(short* dstHi, short* dstLo,
                                            const float* v) {
  short hi[8], lo[8];
  #pragma unroll
  for (int i = 0; i < 8; ++i) {
    const unsigned short h = f2bf(v[i]);
    hi[i] = (short)h;
    lo[i] = (short)f2bf(v[i] - bf2f(h));
  }
  *(uint4*)dstHi = *(const uint4*)hi;
  *(uint4*)dstLo = *(const uint4*)lo;
}

#define LDF(t, va, vb)                                                   \
  do {                                                                   \
    const int ta_ = ((t) < NTK) ? (t) : (t) - NTK;                       \
    const int tb_ = ((t) < 2 * NTK) ? (t) : (t) - 2 * NTK;               \
    const short* Ag_ = Abase + (size_t)ta_ * 2048;                       \
    const short* Bg_ = Bbase + (size_t)tb_ * 2048;                       \
    va[0] = *(const short8*)(Ag_);                                       \
    va[1] = *(const short8*)(Ag_ + 512);                                 \
    va[2] = *(const short8*)(Ag_ + 1024);                                \
    va[3] = *(const short8*)(Ag_ + 1536);                                \
    vb[0] = *(const short8*)(Bg_);                                       \
    vb[1] = *(const short8*)(Bg_ + 512);                                 \
    vb[2] = *(const short8*)(Bg_ + 1024);                                \
    vb[3] = *(const short8*)(Bg_ + 1536);                                \
  } while (0)

#define CMP(va, vb)                                                      \
  do {                                                                   \
    _Pragma("unroll")                                                    \
    for (int s_ = 0; s_ < 4; ++s_)                                       \
      _Pragma("unroll")                                                  \
      for (int u_ = 0; u_ < 4; ++u_)                                     \
        acc[s_][u_] = __builtin_amdgcn_mfma_f32_16x16x32_bf16(           \
            va[s_], vb[u_], acc[s_][u_], 0, 0, 0);                       \
  } while (0)

// ---- one 64x64 output tile (by,bx), per-wave split-K, LDS split-K reduce ----
template <int NTK>
__device__ __forceinline__ void gemm_tile(
    const short* __restrict__ Ablk, const short* __restrict__ Bblk,
    const float* __restrict__ bp, float* __restrict__ H,
    float* __restrict__ cmaxSlot, float* fl, float* red4, int by, int bx)
{
  const int tid  = threadIdx.x;
  const int lane = tid & 63, w = tid >> 6;
  const int rg = lane >> 4, rl = lane & 15;
  const int row0 = by * 64, col0 = bx * 64;

  const short* Abase = Ablk + (size_t)by * (2 * NTK) * 2048 + lane * 8;
  const short* Bbase = Bblk + (size_t)bx * (2 * NTK) * 2048 + lane * 8;

  constexpr int nt = (3 * NTK) >> 2;   // 24 (K=1024) / 12 (K=512)
  const int t0 = w * nt;

  f32x4 acc[4][4];
  #pragma unroll
  for (int s = 0; s < 4; ++s)
    #pragma unroll
    for (int u = 0; u < 4; ++u)
      acc[s][u] = (f32x4){0.f, 0.f, 0.f, 0.f};

  short8 A0[4], B0[4], A1[4], B1[4], A2[4], B2[4];
  LDF(t0 + 0, A0, B0);
  LDF(t0 + 1, A1, B1);
  LDF(t0 + 2, A2, B2);
  #pragma unroll
  for (int i = 0; i < nt; i += 3) {
    CMP(A0, B0);
    if (i + 3 < nt) LDF(t0 + i + 3, A0, B0);
    CMP(A1, B1);
    if (i + 4 < nt) LDF(t0 + i + 4, A1, B1);
    CMP(A2, B2);
    if (i + 5 < nt) LDF(t0 + i + 5, A2, B2);
  }

  // ---- epilogue: 2-pass cross-wave split-K reduce + bias + relu + cmax ----
  float lmax = 0.0f;
  #pragma unroll
  for (int p = 0; p < 2; ++p) {
    if (p == 1) __syncthreads();
    #pragma unroll
    for (int sp = 0; sp < 2; ++sp) {
      const int s = p * 2 + sp;
      #pragma unroll
      for (int u = 0; u < 4; ++u)
        #pragma unroll
        for (int i = 0; i < 4; ++i)
          fl[w * 2176 + (sp * 16 + rg * 4 + i) * 68 + u * 16 + rl] = acc[s][u][i];
    }
    __syncthreads();

    const int rloc = w * 8 + (lane >> 3);      // 0..31
    const int c0 = (lane & 7) * 8;
    f32x4 s0 = {0.f, 0.f, 0.f, 0.f}, s1 = {0.f, 0.f, 0.f, 0.f};
    #pragma unroll
    for (int q = 0; q < 4; ++q) {
      const float* src = fl + q * 2176 + rloc * 68 + c0;
      s0 += *(const f32x4*)src;
      s1 += *(const f32x4*)(src + 4);
    }
    const int gr = row0 + p * 32 + rloc;
    const int gc = col0 + c0;
    const f32x4 bb0 = *(const f32x4*)&bp[gc];
    const f32x4 bb1 = *(const f32x4*)&bp[gc + 4];
    f32x4 o0, o1;
    #pragma unroll
    for (int i = 0; i < 4; ++i) {
      o0[i] = fmaxf(s0[i] + bb0[i], 0.f);
      o1[i] = fmaxf(s1[i] + bb1[i], 0.f);
    }
    float* Hp = H + (size_t)gr * 512 + gc;
    *(f32x4*)Hp = o0;
    *(f32x4*)(Hp + 4) = o1;
    #pragma unroll
    for (int i = 0; i < 4; ++i) {
      if (gc + i < 500) {
        const float v = o0[i], vm = v - 1.0f;
        lmax = fmaxf(lmax, fmaxf(v * v, vm * vm));
      }
      if (gc + 4 + i < 500) {
        const float v = o1[i], vm = v - 1.0f;
        lmax = fmaxf(lmax, fmaxf(v * v, vm * vm));
      }
    }
  }

  #pragma unroll
  for (int off = 32; off; off >>= 1)
    lmax = fmaxf(lmax, __shfl_xor(lmax, off));
  if (lane == 0) red4[w] = lmax;
  __syncthreads();
  if (tid == 0)
    *cmaxSlot = fmaxf(fmaxf(red4[0], red4[1]), fmaxf(red4[2], red4[3]));
  __syncthreads();
}

// ---- prep: grid-stride jobs; thread = slot s -> fully coalesced writes ----
__device__ __forceinline__ void prep_body(const MegaArgs& a, int gridN)
{
  const int sIdx = threadIdx.x;
  const int m = ((sIdx >> 6) << 4) | (sIdx & 15);
  const int g = (sIdx >> 4) & 3;
  for (int job = blockIdx.x; job < 2561; job += gridN) {
    if (job < 2048) {                       // x -> Ablk: (panel, tile)
      const int p = job >> 5, t = job & 31;
      const float* src = a.x + (size_t)(p * 64 + m) * 1024 + t * 32 + g * 8;
      float v[8];
      const f32x4 u0 = *(const f32x4*)src;
      const f32x4 u1 = *(const f32x4*)(src + 4);
      #pragma unroll
      for (int i = 0; i < 4; ++i) { v[i] = u0[i]; v[4 + i] = u1[i]; }
      short* d = a.Ablk + ((size_t)p * 64 + t) * 2048 + sIdx * 8;
      cvt_store16(d, d + 65536, v);         // lo: +32*2048
    } else if (job < 2304) {                // W1 -> B1blk
      const int j = job - 2048;
      const int p = j >> 5, t = j & 31;
      const int n = p * 64 + m;
      float v[8];
      #pragma unroll
      for (int i = 0; i < 8; ++i) {
        const int k = t * 32 + g * 8 + i;
        v[i] = (n < 500) ? a.W1[(size_t)k * 500 + n] : 0.0f;
      }
      short* d = a.B1blk + ((size_t)p * 64 + t) * 2048 + sIdx * 8;
      cvt_store16(d, d + 65536, v);
    } else if (job < 2560) {                // W2/W3 -> B2blk/B3blk
      const int j = (job - 2304) & 127;
      const bool isW3 = (job >= 2432);
      const float* W = isW3 ? a.W3 : a.W2;
      short* Bb = isW3 ? a.B3blk : a.B2blk;
      const int p = j >> 4, t = j & 15;
      const int n = p * 64 + m;
      float v[8];
      #pragma unroll
      for (int i = 0; i < 8; ++i) {
        const int k = t * 32 + g * 8 + i;
        v[i] = (n < 500 && k < 500) ? W[(size_t)k * 500 + n] : 0.0f;
      }
      short* d = Bb + ((size_t)p * 32 + t) * 2048 + sIdx * 8;
      cvt_store16(d, d + 32768, v);         // lo: +16*2048
    } else {                                // bias pad bp[3][512]
      for (int r = 0; r < 6; ++r) {
        const int idx = r * 256 + threadIdx.x;
        const int L = idx >> 9, c = idx & 511;
        const float* src = (L == 0) ? a.b1 : (L == 1) ? a.b2 : a.b3;
        a.bp[idx] = (c < 500) ? src[c] : 0.0f;
      }
    }
  }
}

// ---- sinkhorn: 4 rows per wave (ILP x4), exact joint bitwise early-exit ----
template <bool FINAL>
__device__ __forceinline__ void sinkhorn_body(
    const MegaArgs& a, const float* cmaxArr, short* outBlk)
{
  const int w    = threadIdx.x >> 6;
  const int lane = threadIdx.x & 63;
  const int r0   = (blockIdx.x * 4 + w) * 4;   // rows r0..r0+3

  const f32x4 cc0 = *(const f32x4*)&cmaxArr[lane * 8];
  const f32x4 cc1 = *(const f32x4*)&cmaxArr[lane * 8 + 4];
  float cmax = fmaxf(fmaxf(fmaxf(cc0[0], cc0[1]), fmaxf(cc0[2], cc0[3])),
                     fmaxf(fmaxf(cc1[0], cc1[1]), fmaxf(cc1[2], cc1[3])));
  #pragma unroll
  for (int off = 32; off; off >>= 1)
    cmax = fmaxf(cmax, __shfl_xor(cmax, off));

  const float s   = (float)a.sparse[0];
  const float inv = 1.0f / (0.1f * cmax);

  float h[4][8], R[4][8];
  #pragma unroll
  for (int r = 0; r < 4; ++r) {
    const float* Hr = a.H + (size_t)(r0 + r) * 512 + lane * 8;
    const f32x4 u0 = *(const f32x4*)Hr;
    const f32x4 u1 = *(const f32x4*)(Hr + 4);
    #pragma unroll
    for (int i = 0; i < 4; ++i) { h[r][i] = u0[i]; h[r][4 + i] = u1[i]; }
  }
  #pragma unroll
  for (int r = 0; r < 4; ++r)
    #pragma unroll
    for (int j = 0; j < 8; ++j)
      R[r][j] = __expf((2.0f * h[r][j] - 1.0f) * inv);

  const int nval = min(max(500 - lane * 8, 0), 8);

  float t[4] = {1.f, 1.f, 1.f, 1.f};
  float A[4];
  for (int it = 0; it < 50; ++it) {
    #pragma unroll
    for (int r = 0; r < 4; ++r) A[r] = 0.0f;
    #pragma unroll
    for (int j = 0; j < 8; ++j) {
      #pragma unroll
      for (int r = 0; r < 4; ++r) {
        float wv = __builtin_amdgcn_rcpf(fmaf(t[r], R[r][j], 1.0f));
        if (j >= nval) wv = 0.0f;
        A[r] += wv;
      }
    }
    #pragma unroll
    for (int off = 32; off; off >>= 1) {
      #pragma unroll
      for (int r = 0; r < 4; ++r) A[r] += __shfl_xor(A[r], off);
    }
    if (it == 49) break;
    float tn[4];
    #pragma unroll
    for (int r = 0; r < 4; ++r)
      tn[r] = 0.25f * A[r] * t[r] * __builtin_amdgcn_rcpf(500.0f - A[r]);
    bool same = true;
    #pragma unroll
    for (int r = 0; r < 4; ++r)
      same = same && (__float_as_uint(tn[r]) == __float_as_uint(t[r]));
    if (same) break;                         // exact fixed point (all rows)
    #pragma unroll
    for (int r = 0; r < 4; ++r) t[r] = tn[r];
  }

  if (!FINAL) {
    const int tt = lane >> 2, g = lane & 3;
    #pragma unroll
    for (int r = 0; r < 4; ++r) {
      const float kA = 400.0f / A[r];
      const int row = r0 + r;
      short hi[8], lo[8];
      #pragma unroll
      for (int j = 0; j < 8; ++j) {
        const float wv = __builtin_amdgcn_rcpf(fmaf(t[r], R[r][j], 1.0f));
        float o = h[r][j] * (s * (kA * wv) + (1.0f - s));
        if (j >= nval) o = 0.0f;
        const unsigned short hh = f2bf(o);
        hi[j] = (short)hh;
        lo[j] = (short)f2bf(o - bf2f(hh));
      }
      const int p = row >> 6, m = row & 63;
      const int slot = ((m >> 4) << 6) + (g << 4) + (m & 15);
      short* o = outBlk + ((size_t)p * 32 + tt) * 2048 + slot * 8;
      *(uint4*)o           = *(const uint4*)hi;
      *(uint4*)(o + 32768) = *(const uint4*)lo;   // lo tiles: +16*2048
    }
  } else {
    #pragma unroll
    for (int r = 0; r < 4; ++r) {
      const float kA = 400.0f / A[r];
      float acc[10];
      #pragma unroll
      for (int o = 0; o < 10; ++o) acc[o] = 0.0f;
      const float* Wr = a.W4 + (size_t)lane * 80;
      #pragma unroll
      for (int j = 0; j < 8; ++j) {
        if (j < nval) {
          const float wv = __builtin_amdgcn_rcpf(fmaf(t[r], R[r][j], 1.0f));
          const float mhv = h[r][j] * (s * (kA * wv) + (1.0f - s));
          #pragma unroll
          for (int o = 0; o < 10; ++o)
            acc[o] = fmaf(mhv, Wr[j * 10 + o], acc[o]);
        }
      }
      #pragma unroll
      for (int o = 0; o < 10; ++o) {
        #pragma unroll
        for (int off = 32; off; off >>= 1) acc[o] += __shfl_xor(acc[o], off);
      }
      if (lane == 0) {
        #pragma unroll
        for (int o = 0; o < 10; ++o)
          a.out[(size_t)(r0 + r) * 10 + o] = acc[o] + a.b4[o];
      }
    }
  }
}

// ---------------------------------------------------------------------------
// Cooperative kernel: 256 blocks x 256 threads (1 block/CU co-residency).
// ---------------------------------------------------------------------------
__global__ __launch_bounds__(256, 1) void meganet(MegaArgs a)
{
  __shared__ __align__(16) float fl[8704];   // gemm epilogue: 4 x [32][68]
  __shared__ float red4[4];
  cg::grid_group grid = cg::this_grid();

  prep_body(a, 256);
  grid.sync();

  const int by = blockIdx.x & 63, bxh = blockIdx.x >> 6;   // bxh 0..3
  gemm_tile<32>(a.Ablk, a.B1blk, a.bp, a.H,
                &a.cmaxA[blockIdx.x], fl, red4, by, bxh * 2);
  gemm_tile<32>(a.Ablk, a.B1blk, a.bp, a.H,
                &a.cmaxA[256 + blockIdx.x], fl, red4, by, bxh * 2 + 1);
  grid.sync();
  sinkhorn_body<false>(a, a.cmaxA, a.Hmblk);
  grid.sync();

  gemm_tile<16>(a.Hmblk, a.B2blk, a.bp + 512, a.H,
                &a.cmaxA[512 + blockIdx.x], fl, red4, by, bxh * 2);
  gemm_tile<16>(a.Hmblk, a.B2blk, a.bp + 512, a.H,
                &a.cmaxA[768 + blockIdx.x], fl, red4, by, bxh * 2 + 1);
  grid.sync();
  sinkhorn_body<false>(a, a.cmaxA + 512, a.Hmblk);
  grid.sync();

  gemm_tile<16>(a.Hmblk, a.B3blk, a.bp + 1024, a.H,
                &a.cmaxA[1024 + blockIdx.x], fl, red4, by, bxh * 2);
  gemm_tile<16>(a.Hmblk, a.B3blk, a.bp + 1024, a.H,
                &a.cmaxA[1280 + blockIdx.x], fl, red4, by, bxh * 2 + 1);
  grid.sync();
  sinkhorn_body<true>(a, a.cmaxA + 1024, nullptr);
}

// ---------------------------------------------------------------------------
// Fallback multi-kernel path (round-7 structure).
// ---------------------------------------------------------------------------
__global__ __launch_bounds__(256) void prep_k(MegaArgs a)
{
  prep_body(a, gridDim.x);
}

template <int NTK>
__global__ __launch_bounds__(256, 2) void gemm_k(
    const short* __restrict__ Ablk, const short* __restrict__ Bblk,
    const float* __restrict__ bp, float* __restrict__ H,
    float* __restrict__ cmaxArr)
{
  __shared__ __align__(16) float fl[8704];
  __shared__ float red4[4];
  gemm_tile<NTK>(Ablk, Bblk, bp, H, &cmaxArr[blockIdx.x], fl, red4,
                 blockIdx.x & 63, blockIdx.x >> 6);
}

template <bool FINAL>
__global__ __launch_bounds__(256) void sinkhorn_k(
    MegaArgs a, const float* __restrict__ cmaxArr, short* __restrict__ outBlk)
{
  sinkhorn_body<FINAL>(a, cmaxArr, outBlk);
}

extern "C" void kernel_launch(void* const* d_in, const int* in_sizes, int n_in,
                              void* d_out, int out_size, void* d_ws, size_t ws_size,
                              hipStream_t stream)
{
  char* ws = (char*)d_ws;

  MegaArgs a;
  a.x  = (const float*)d_in[0];
  a.W1 = (const float*)d_in[1];
  a.b1 = (const float*)d_in[2];
  a.W2 = (const float*)d_in[3];
  a.b2 = (const float*)d_in[4];
  a.W3 = (const float*)d_in[5];
  a.b3 = (const float*)d_in[6];
  a.W4 = (const float*)d_in[7];
  a.b4 = (const float*)d_in[8];
  a.sparse = (const int*)d_in[9];
  a.out = (float*)d_out;

  a.cmaxA = (float*)ws;                                      // [3][512]
  a.bp    = (float*)(ws + 8192);                             // [3][512]
  a.Ablk  = (short*)(ws + 16384);                            // 16MB
  a.B1blk = a.Ablk  + (size_t)64 * 64 * 2048;                // 2MB
  a.B2blk = a.B1blk + (size_t)8 * 64 * 2048;                 // 1MB
  a.B3blk = a.B2blk + (size_t)8 * 32 * 2048;                 // 1MB
  a.H     = (float*)(a.B3blk + (size_t)8 * 32 * 2048);       // 8MB
  a.Hmblk = (short*)(a.H + (size_t)4096 * 512);              // 8MB

  // capability gate (host-side queries only; identical decision every call)
  int dev = 0, coopAttr = 0, ncu = 0, nb = 0;
  hipGetDevice(&dev);
  hipDeviceGetAttribute(&coopAttr, hipDeviceAttributeCooperativeLaunch, dev);
  hipDeviceGetAttribute(&ncu, hipDeviceAttributeMultiprocessorCount, dev);
  hipOccupancyMaxActiveBlocksPerMultiprocessor(&nb, meganet, 256, 0);

  if (coopAttr && (long)nb * (long)ncu >= 256) {
    void* kargs[] = { (void*)&a };
    hipLaunchCooperativeKernel((const void*)meganet, dim3(256), dim3(256),
                               kargs, 0, stream);
  } else {
    prep_k<<<512, 256, 0, stream>>>(a);
    gemm_k<32><<<512, 256, 0, stream>>>(a.Ablk, a.B1blk, a.bp, a.H, a.cmaxA);
    sinkhorn_k<false><<<256, 256, 0, stream>>>(a, a.cmaxA, a.Hmblk);
    gemm_k<16><<<512, 256, 0, stream>>>(a.Hmblk, a.B2blk, a.bp + 512, a.H,
                                        a.cmaxA + 512);
    sinkhorn_k<false><<<256, 256, 0, stream>>>(a, a.cmaxA + 512, a.Hmblk);
    gemm_k<16><<<512, 256, 0, stream>>>(a.Hmblk, a.B3blk, a.bp + 1024, a.H,
                                        a.cmaxA + 1024);
    sinkhorn_k<true><<<256, 256, 0, stream>>>(a, a.cmaxA + 1024, nullptr);
  }
}

// Round 10
// 184.571 us; speedup vs baseline: 1.0143x; 1.0143x over previous
//
#include <hip/hip_runtime.h>
#include <math.h>

// ---------------------------------------------------------------------------
// NeuralNet_62045097558546 on MI355X (gfx950)
// 3x (GEMM+bias+ReLU+cmax -> soft-topk mask) -> GEMM+bias
// GEMMs: bf16 MFMA split precision, C = Ahi*Bhi + Ahi*Blo + Alo*Bhi as one
// bf16 GEMM over K' = 3K. Physical: compact [hi(NTK)|lo(NTK)] 4KB tiles.
//   A'=[hi|hi|lo]: ta = t<NTK ? t : t-NTK
//   B'=[hi|lo|hi]: tb = t<2NTK ? t : t-2NTK
// FRAGMENT-ORDER BLOCKED LAYOUT: panel p (64 rows) -> tile t (32 k') ->
//   slot s = (m>>4)*64 + g*16 + (m&15) (8 shorts: row m, k-chunk g).
//   Fragment load for sub-tile s16 = ONE contiguous 1KB block per 64 lanes.
// K-loop: no LDS/barriers/atomics; compile-time 3-stage register pipeline.
// Multi-kernel path (cooperative fusion measured SLOWER: 4 waves/CU + grid
// sync drain > launch gaps. rounds 8/9).
// ---------------------------------------------------------------------------

typedef __attribute__((ext_vector_type(8))) short short8;
typedef __attribute__((ext_vector_type(4))) float f32x4;

__device__ __forceinline__ unsigned short f2bf(float f) {
  unsigned u = __float_as_uint(f);
  u += 0x7fffu + ((u >> 16) & 1u);
  return (unsigned short)(u >> 16);
}
__device__ __forceinline__ float bf2f(unsigned short s) {
  return __uint_as_float(((unsigned)s) << 16);
}

struct MegaArgs {
  const float *x, *W1, *b1, *W2, *b2, *W3, *b3, *W4, *b4;
  const int* sparse;
  float* out;
  short *Ablk, *B1blk, *B2blk, *B3blk, *Hmblk;
  float *H, *bp, *cmaxA;
};

__device__ __forceinline__ void cvt_store16(short* dstHi, short* dstLo,
                                            const float* v) {
  short hi[8], lo[8];
  #pragma unroll
  for (int i = 0; i < 8; ++i) {
    const unsigned short h = f2bf(v[i]);
    hi[i] = (short)h;
    lo[i] = (short)f2bf(v[i] - bf2f(h));
  }
  *(uint4*)dstHi = *(const uint4*)hi;
  *(uint4*)dstLo = *(const uint4*)lo;
}

#define LDF(t, va, vb)                                                   \
  do {                                                                   \
    const int ta_ = ((t) < NTK) ? (t) : (t) - NTK;                       \
    const int tb_ = ((t) < 2 * NTK) ? (t) : (t) - 2 * NTK;               \
    const short* Ag_ = Abase + (size_t)ta_ * 2048;                       \
    const short* Bg_ = Bbase + (size_t)tb_ * 2048;                       \
    va[0] = *(const short8*)(Ag_);                                       \
    va[1] = *(const short8*)(Ag_ + 512);                                 \
    va[2] = *(const short8*)(Ag_ + 1024);                                \
    va[3] = *(const short8*)(Ag_ + 1536);                                \
    vb[0] = *(const short8*)(Bg_);                                       \
    vb[1] = *(const short8*)(Bg_ + 512);                                 \
    vb[2] = *(const short8*)(Bg_ + 1024);                                \
    vb[3] = *(const short8*)(Bg_ + 1536);                                \
  } while (0)

#define CMP(va, vb)                                                      \
  do {                                                                   \
    _Pragma("unroll")                                                    \
    for (int s_ = 0; s_ < 4; ++s_)                                       \
      _Pragma("unroll")                                                  \
      for (int u_ = 0; u_ < 4; ++u_)                                     \
        acc[s_][u_] = __builtin_amdgcn_mfma_f32_16x16x32_bf16(           \
            va[s_], vb[u_], acc[s_][u_], 0, 0, 0);                       \
  } while (0)

// ---- GEMM kernel: one 64x64 tile/block, per-wave split-K, reg pipeline ----
template <int NTK>
__global__ __launch_bounds__(256, 2) void gemm_k(
    const short* __restrict__ Ablk, const short* __restrict__ Bblk,
    const float* __restrict__ bp, float* __restrict__ H,
    float* __restrict__ cmaxArr)
{
  __shared__ __align__(16) float fl[8704];   // epilogue: 4 x [32][68]
  __shared__ float red4[4];

  const int tid  = threadIdx.x;
  const int lane = tid & 63, w = tid >> 6;
  const int rg = lane >> 4, rl = lane & 15;

  // by fast: XCD (blockIdx%8) keeps its 8 A row-panels L2-resident.
  const int by = blockIdx.x & 63, bx = blockIdx.x >> 6;
  const int row0 = by * 64, col0 = bx * 64;

  const short* Abase = Ablk + (size_t)by * (2 * NTK) * 2048 + lane * 8;
  const short* Bbase = Bblk + (size_t)bx * (2 * NTK) * 2048 + lane * 8;

  constexpr int nt = (3 * NTK) >> 2;   // 24 (K=1024) / 12 (K=512)
  const int t0 = w * nt;

  f32x4 acc[4][4];
  #pragma unroll
  for (int s = 0; s < 4; ++s)
    #pragma unroll
    for (int u = 0; u < 4; ++u)
      acc[s][u] = (f32x4){0.f, 0.f, 0.f, 0.f};

  short8 A0[4], B0[4], A1[4], B1[4], A2[4], B2[4];
  LDF(t0 + 0, A0, B0);
  LDF(t0 + 1, A1, B1);
  LDF(t0 + 2, A2, B2);
  #pragma unroll
  for (int i = 0; i < nt; i += 3) {
    CMP(A0, B0);
    if (i + 3 < nt) LDF(t0 + i + 3, A0, B0);
    CMP(A1, B1);
    if (i + 4 < nt) LDF(t0 + i + 4, A1, B1);
    CMP(A2, B2);
    if (i + 5 < nt) LDF(t0 + i + 5, A2, B2);
  }

  // ---- epilogue: 2-pass cross-wave split-K reduce + bias + relu + cmax ----
  float lmax = 0.0f;
  #pragma unroll
  for (int p = 0; p < 2; ++p) {
    if (p == 1) __syncthreads();
    #pragma unroll
    for (int sp = 0; sp < 2; ++sp) {
      const int s = p * 2 + sp;
      #pragma unroll
      for (int u = 0; u < 4; ++u)
        #pragma unroll
        for (int i = 0; i < 4; ++i)
          fl[w * 2176 + (sp * 16 + rg * 4 + i) * 68 + u * 16 + rl] = acc[s][u][i];
    }
    __syncthreads();

    const int rloc = w * 8 + (lane >> 3);      // 0..31
    const int c0 = (lane & 7) * 8;
    f32x4 s0 = {0.f, 0.f, 0.f, 0.f}, s1 = {0.f, 0.f, 0.f, 0.f};
    #pragma unroll
    for (int q = 0; q < 4; ++q) {
      const float* src = fl + q * 2176 + rloc * 68 + c0;
      s0 += *(const f32x4*)src;
      s1 += *(const f32x4*)(src + 4);
    }
    const int gr = row0 + p * 32 + rloc;
    const int gc = col0 + c0;
    const f32x4 bb0 = *(const f32x4*)&bp[gc];
    const f32x4 bb1 = *(const f32x4*)&bp[gc + 4];
    f32x4 o0, o1;
    #pragma unroll
    for (int i = 0; i < 4; ++i) {
      o0[i] = fmaxf(s0[i] + bb0[i], 0.f);
      o1[i] = fmaxf(s1[i] + bb1[i], 0.f);
    }
    float* Hp = H + (size_t)gr * 512 + gc;
    *(f32x4*)Hp = o0;
    *(f32x4*)(Hp + 4) = o1;
    #pragma unroll
    for (int i = 0; i < 4; ++i) {
      if (gc + i < 500) {
        const float v = o0[i], vm = v - 1.0f;
        lmax = fmaxf(lmax, fmaxf(v * v, vm * vm));
      }
      if (gc + 4 + i < 500) {
        const float v = o1[i], vm = v - 1.0f;
        lmax = fmaxf(lmax, fmaxf(v * v, vm * vm));
      }
    }
  }

  #pragma unroll
  for (int off = 32; off; off >>= 1)
    lmax = fmaxf(lmax, __shfl_xor(lmax, off));
  if (lane == 0) red4[w] = lmax;
  __syncthreads();
  if (tid == 0)
    cmaxArr[blockIdx.x] =
        fmaxf(fmaxf(red4[0], red4[1]), fmaxf(red4[2], red4[3]));
}

// ---- prep: job = one 4KB tile; thread = slot -> fully coalesced writes ----
__global__ __launch_bounds__(256) void prep_k(MegaArgs a)
{
  const int sIdx = threadIdx.x;
  const int m = ((sIdx >> 6) << 4) | (sIdx & 15);
  const int g = (sIdx >> 4) & 3;
  for (int job = blockIdx.x; job < 2561; job += gridDim.x) {
    if (job < 2048) {                       // x -> Ablk: (panel, tile)
      const int p = job >> 5, t = job & 31;
      const float* src = a.x + (size_t)(p * 64 + m) * 1024 + t * 32 + g * 8;
      float v[8];
      const f32x4 u0 = *(const f32x4*)src;
      const f32x4 u1 = *(const f32x4*)(src + 4);
      #pragma unroll
      for (int i = 0; i < 4; ++i) { v[i] = u0[i]; v[4 + i] = u1[i]; }
      short* d = a.Ablk + ((size_t)p * 64 + t) * 2048 + sIdx * 8;
      cvt_store16(d, d + 65536, v);         // lo: +32*2048
    } else if (job < 2304) {                // W1 -> B1blk
      const int j = job - 2048;
      const int p = j >> 5, t = j & 31;
      const int n = p * 64 + m;
      float v[8];
      #pragma unroll
      for (int i = 0; i < 8; ++i) {
        const int k = t * 32 + g * 8 + i;
        v[i] = (n < 500) ? a.W1[(size_t)k * 500 + n] : 0.0f;
      }
      short* d = a.B1blk + ((size_t)p * 64 + t) * 2048 + sIdx * 8;
      cvt_store16(d, d + 65536, v);
    } else if (job < 2560) {                // W2/W3 -> B2blk/B3blk
      const int j = (job - 2304) & 127;
      const bool isW3 = (job >= 2432);
      const float* W = isW3 ? a.W3 : a.W2;
      short* Bb = isW3 ? a.B3blk : a.B2blk;
      const int p = j >> 4, t = j & 15;
      const int n = p * 64 + m;
      float v[8];
      #pragma unroll
      for (int i = 0; i < 8; ++i) {
        const int k = t * 32 + g * 8 + i;
        v[i] = (n < 500 && k < 500) ? W[(size_t)k * 500 + n] : 0.0f;
      }
      short* d = Bb + ((size_t)p * 32 + t) * 2048 + sIdx * 8;
      cvt_store16(d, d + 32768, v);         // lo: +16*2048
    } else {                                // bias pad bp[3][512]
      for (int r = 0; r < 6; ++r) {
        const int idx = r * 256 + threadIdx.x;
        const int L = idx >> 9, c = idx & 511;
        const float* src = (L == 0) ? a.b1 : (L == 1) ? a.b2 : a.b3;
        a.bp[idx] = (c < 500) ? src[c] : 0.0f;
      }
    }
  }
}

// ---- sinkhorn: 4 rows per wave (ILP x4), exact joint bitwise early-exit ----
template <bool FINAL>
__global__ __launch_bounds__(256) void sinkhorn_k(
    MegaArgs a, const float* __restrict__ cmaxArr, short* __restrict__ outBlk)
{
  const int w    = threadIdx.x >> 6;
  const int lane = threadIdx.x & 63;
  const int r0   = (blockIdx.x * 4 + w) * 4;   // rows r0..r0+3

  const f32x4 cc0 = *(const f32x4*)&cmaxArr[lane * 8];
  const f32x4 cc1 = *(const f32x4*)&cmaxArr[lane * 8 + 4];
  float cmax = fmaxf(fmaxf(fmaxf(cc0[0], cc0[1]), fmaxf(cc0[2], cc0[3])),
                     fmaxf(fmaxf(cc1[0], cc1[1]), fmaxf(cc1[2], cc1[3])));
  #pragma unroll
  for (int off = 32; off; off >>= 1)
    cmax = fmaxf(cmax, __shfl_xor(cmax, off));

  const float s   = (float)a.sparse[0];
  const float inv = 1.0f / (0.1f * cmax);

  float h[4][8], R[4][8];
  #pragma unroll
  for (int r = 0; r < 4; ++r) {
    const float* Hr = a.H + (size_t)(r0 + r) * 512 + lane * 8;
    const f32x4 u0 = *(const f32x4*)Hr;
    const f32x4 u1 = *(const f32x4*)(Hr + 4);
    #pragma unroll
    for (int i = 0; i < 4; ++i) { h[r][i] = u0[i]; h[r][4 + i] = u1[i]; }
  }
  #pragma unroll
  for (int r = 0; r < 4; ++r)
    #pragma unroll
    for (int j = 0; j < 8; ++j)
      R[r][j] = __expf((2.0f * h[r][j] - 1.0f) * inv);

  const int nval = min(max(500 - lane * 8, 0), 8);

  float t[4] = {1.f, 1.f, 1.f, 1.f};
  float A[4];
  for (int it = 0; it < 50; ++it) {
    #pragma unroll
    for (int r = 0; r < 4; ++r) A[r] = 0.0f;
    #pragma unroll
    for (int j = 0; j < 8; ++j) {
      #pragma unroll
      for (int r = 0; r < 4; ++r) {
        float wv = __builtin_amdgcn_rcpf(fmaf(t[r], R[r][j], 1.0f));
        if (j >= nval) wv = 0.0f;
        A[r] += wv;
      }
    }
    #pragma unroll
    for (int off = 32; off; off >>= 1) {
      #pragma unroll
      for (int r = 0; r < 4; ++r) A[r] += __shfl_xor(A[r], off);
    }
    if (it == 49) break;
    float tn[4];
    #pragma unroll
    for (int r = 0; r < 4; ++r)
      tn[r] = 0.25f * A[r] * t[r] * __builtin_amdgcn_rcpf(500.0f - A[r]);
    bool same = true;
    #pragma unroll
    for (int r = 0; r < 4; ++r)
      same = same && (__float_as_uint(tn[r]) == __float_as_uint(t[r]));
    if (same) break;                         // exact fixed point (all rows)
    #pragma unroll
    for (int r = 0; r < 4; ++r) t[r] = tn[r];
  }

  if (!FINAL) {
    const int tt = lane >> 2, g = lane & 3;
    #pragma unroll
    for (int r = 0; r < 4; ++r) {
      const float kA = 400.0f / A[r];
      const int row = r0 + r;
      short hi[8], lo[8];
      #pragma unroll
      for (int j = 0; j < 8; ++j) {
        const float wv = __builtin_amdgcn_rcpf(fmaf(t[r], R[r][j], 1.0f));
        float o = h[r][j] * (s * (kA * wv) + (1.0f - s));
        if (j >= nval) o = 0.0f;
        const unsigned short hh = f2bf(o);
        hi[j] = (short)hh;
        lo[j] = (short)f2bf(o - bf2f(hh));
      }
      const int p = row >> 6, m = row & 63;
      const int slot = ((m >> 4) << 6) + (g << 4) + (m & 15);
      short* o = outBlk + ((size_t)p * 32 + tt) * 2048 + slot * 8;
      *(uint4*)o           = *(const uint4*)hi;
      *(uint4*)(o + 32768) = *(const uint4*)lo;   // lo tiles: +16*2048
    }
  } else {
    #pragma unroll
    for (int r = 0; r < 4; ++r) {
      const float kA = 400.0f / A[r];
      float acc[10];
      #pragma unroll
      for (int o = 0; o < 10; ++o) acc[o] = 0.0f;
      const float* Wr = a.W4 + (size_t)lane * 80;
      #pragma unroll
      for (int j = 0; j < 8; ++j) {
        if (j < nval) {
          const float wv = __builtin_amdgcn_rcpf(fmaf(t[r], R[r][j], 1.0f));
          const float mhv = h[r][j] * (s * (kA * wv) + (1.0f - s));
          #pragma unroll
          for (int o = 0; o < 10; ++o)
            acc[o] = fmaf(mhv, Wr[j * 10 + o], acc[o]);
        }
      }
      #pragma unroll
      for (int o = 0; o < 10; ++o) {
        #pragma unroll
        for (int off = 32; off; off >>= 1) acc[o] += __shfl_xor(acc[o], off);
      }
      if (lane == 0) {
        #pragma unroll
        for (int o = 0; o < 10; ++o)
          a.out[(size_t)(r0 + r) * 10 + o] = acc[o] + a.b4[o];
      }
    }
  }
}

extern "C" void kernel_launch(void* const* d_in, const int* in_sizes, int n_in,
                              void* d_out, int out_size, void* d_ws, size_t ws_size,
                              hipStream_t stream)
{
  char* ws = (char*)d_ws;

  MegaArgs a;
  a.x  = (const float*)d_in[0];
  a.W1 = (const float*)d_in[1];
  a.b1 = (const float*)d_in[2];
  a.W2 = (const float*)d_in[3];
  a.b2 = (const float*)d_in[4];
  a.W3 = (const float*)d_in[5];
  a.b3 = (const float*)d_in[6];
  a.W4 = (const float*)d_in[7];
  a.b4 = (const float*)d_in[8];
  a.sparse = (const int*)d_in[9];
  a.out = (float*)d_out;

  a.cmaxA = (float*)ws;                                      // [3][512]
  a.bp    = (float*)(ws + 8192);                             // [3][512]
  a.Ablk  = (short*)(ws + 16384);                            // 16MB
  a.B1blk = a.Ablk  + (size_t)64 * 64 * 2048;                // 2MB
  a.B2blk = a.B1blk + (size_t)8 * 64 * 2048;                 // 1MB
  a.B3blk = a.B2blk + (size_t)8 * 32 * 2048;                 // 1MB
  a.H     = (float*)(a.B3blk + (size_t)8 * 32 * 2048);       // 8MB
  a.Hmblk = (short*)(a.H + (size_t)4096 * 512);              // 8MB

  prep_k<<<512, 256, 0, stream>>>(a);
  gemm_k<32><<<512, 256, 0, stream>>>(a.Ablk, a.B1blk, a.bp, a.H, a.cmaxA);
  sinkhorn_k<false><<<256, 256, 0, stream>>>(a, a.cmaxA, a.Hmblk);
  gemm_k<16><<<512, 256, 0, stream>>>(a.Hmblk, a.B2blk, a.bp + 512, a.H,
                                      a.cmaxA + 512);
  sinkhorn_k<false><<<256, 256, 0, stream>>>(a, a.cmaxA + 512, a.Hmblk);
  gemm_k<16><<<512, 256, 0, stream>>>(a.Hmblk, a.B3blk, a.bp + 1024, a.H,
                                      a.cmaxA + 1024);
  sinkhorn_k<true><<<256, 256, 0, stream>>>(a, a.cmaxA + 1024, nullptr);
}

// Round 11
// 149.542 us; speedup vs baseline: 1.2519x; 1.2342x over previous
//
#include <hip/hip_runtime.h>
#include <math.h>

// ---------------------------------------------------------------------------
// NeuralNet_62045097558546 on MI355X (gfx950)
// 3x (GEMM+bias+ReLU+cmax -> soft-topk mask) -> GEMM+bias
// GEMMs: bf16 MFMA split precision, C = Ahi*Bhi + Ahi*Blo + Alo*Bhi as one
// bf16 GEMM over K' = 3K. Physical: compact [hi(NTK)|lo(NTK)] 4KB tiles.
//   A'=[hi|hi|lo]: ta = t<NTK ? t : t-NTK
//   B'=[hi|lo|hi]: tb = t<2NTK ? t : t-2NTK
// FRAGMENT-ORDER BLOCKED LAYOUT: panel p (64 rows) -> tile t (32 k') ->
//   slot s = (m>>4)*64 + g*16 + (m&15) (8 shorts: row m, k-chunk g).
//   Fragment load for sub-tile s16 = ONE contiguous 1KB block per 64 lanes.
// GEMM K-loop: no LDS/barriers/atomics; compile-time 3-stage reg pipeline.
//
// Soft-topk: the 50-step 2-anchor Sinkhorn collapses to the scalar root of
// A(t) = sum 1/(1+t*R_i) = 400 (the k-constraint). Solved by NEWTON:
//   A' = -(A - S)/t with S = sum w^2, w = 1/(1+tR)  (convex, decreasing ->
//   globally convergent from the g>=0 side; clamp guards the first step).
// ~5-8 iterations to bitwise fixed point vs ~25-49 for the plain iteration
// (r10 counters: 3 x 49.6us sinkhorn = 80% of runtime, 1 wave/SIMD stalls
// on the shuffle chain). 1 row/wave, 1024 blocks (4 waves/SIMD).
// ---------------------------------------------------------------------------

typedef __attribute__((ext_vector_type(8))) short short8;
typedef __attribute__((ext_vector_type(4))) float f32x4;

__device__ __forceinline__ unsigned short f2bf(float f) {
  unsigned u = __float_as_uint(f);
  u += 0x7fffu + ((u >> 16) & 1u);
  return (unsigned short)(u >> 16);
}
__device__ __forceinline__ float bf2f(unsigned short s) {
  return __uint_as_float(((unsigned)s) << 16);
}

struct MegaArgs {
  const float *x, *W1, *b1, *W2, *b2, *W3, *b3, *W4, *b4;
  const int* sparse;
  float* out;
  short *Ablk, *B1blk, *B2blk, *B3blk, *Hmblk;
  float *H, *bp, *cmaxA;
};

__device__ __forceinline__ void cvt_store16(short* dstHi, short* dstLo,
                                            const float* v) {
  short hi[8], lo[8];
  #pragma unroll
  for (int i = 0; i < 8; ++i) {
    const unsigned short h = f2bf(v[i]);
    hi[i] = (short)h;
    lo[i] = (short)f2bf(v[i] - bf2f(h));
  }
  *(uint4*)dstHi = *(const uint4*)hi;
  *(uint4*)dstLo = *(const uint4*)lo;
}

#define LDF(t, va, vb)                                                   \
  do {                                                                   \
    const int ta_ = ((t) < NTK) ? (t) : (t) - NTK;                       \
    const int tb_ = ((t) < 2 * NTK) ? (t) : (t) - 2 * NTK;               \
    const short* Ag_ = Abase + (size_t)ta_ * 2048;                       \
    const short* Bg_ = Bbase + (size_t)tb_ * 2048;                       \
    va[0] = *(const short8*)(Ag_);                                       \
    va[1] = *(const short8*)(Ag_ + 512);                                 \
    va[2] = *(const short8*)(Ag_ + 1024);                                \
    va[3] = *(const short8*)(Ag_ + 1536);                                \
    vb[0] = *(const short8*)(Bg_);                                       \
    vb[1] = *(const short8*)(Bg_ + 512);                                 \
    vb[2] = *(const short8*)(Bg_ + 1024);                                \
    vb[3] = *(const short8*)(Bg_ + 1536);                                \
  } while (0)

#define CMP(va, vb)                                                      \
  do {                                                                   \
    _Pragma("unroll")                                                    \
    for (int s_ = 0; s_ < 4; ++s_)                                       \
      _Pragma("unroll")                                                  \
      for (int u_ = 0; u_ < 4; ++u_)                                     \
        acc[s_][u_] = __builtin_amdgcn_mfma_f32_16x16x32_bf16(           \
            va[s_], vb[u_], acc[s_][u_], 0, 0, 0);                       \
  } while (0)

// ---- GEMM kernel: one 64x64 tile/block, per-wave split-K, reg pipeline ----
template <int NTK>
__global__ __launch_bounds__(256, 2) void gemm_k(
    const short* __restrict__ Ablk, const short* __restrict__ Bblk,
    const float* __restrict__ bp, float* __restrict__ H,
    float* __restrict__ cmaxArr)
{
  __shared__ __align__(16) float fl[8704];   // epilogue: 4 x [32][68]
  __shared__ float red4[4];

  const int tid  = threadIdx.x;
  const int lane = tid & 63, w = tid >> 6;
  const int rg = lane >> 4, rl = lane & 15;

  // by fast: XCD (blockIdx%8) keeps its 8 A row-panels L2-resident.
  const int by = blockIdx.x & 63, bx = blockIdx.x >> 6;
  const int row0 = by * 64, col0 = bx * 64;

  const short* Abase = Ablk + (size_t)by * (2 * NTK) * 2048 + lane * 8;
  const short* Bbase = Bblk + (size_t)bx * (2 * NTK) * 2048 + lane * 8;

  constexpr int nt = (3 * NTK) >> 2;   // 24 (K=1024) / 12 (K=512)
  const int t0 = w * nt;

  f32x4 acc[4][4];
  #pragma unroll
  for (int s = 0; s < 4; ++s)
    #pragma unroll
    for (int u = 0; u < 4; ++u)
      acc[s][u] = (f32x4){0.f, 0.f, 0.f, 0.f};

  short8 A0[4], B0[4], A1[4], B1[4], A2[4], B2[4];
  LDF(t0 + 0, A0, B0);
  LDF(t0 + 1, A1, B1);
  LDF(t0 + 2, A2, B2);
  #pragma unroll
  for (int i = 0; i < nt; i += 3) {
    CMP(A0, B0);
    if (i + 3 < nt) LDF(t0 + i + 3, A0, B0);
    CMP(A1, B1);
    if (i + 4 < nt) LDF(t0 + i + 4, A1, B1);
    CMP(A2, B2);
    if (i + 5 < nt) LDF(t0 + i + 5, A2, B2);
  }

  // ---- epilogue: 2-pass cross-wave split-K reduce + bias + relu + cmax ----
  float lmax = 0.0f;
  #pragma unroll
  for (int p = 0; p < 2; ++p) {
    if (p == 1) __syncthreads();
    #pragma unroll
    for (int sp = 0; sp < 2; ++sp) {
      const int s = p * 2 + sp;
      #pragma unroll
      for (int u = 0; u < 4; ++u)
        #pragma unroll
        for (int i = 0; i < 4; ++i)
          fl[w * 2176 + (sp * 16 + rg * 4 + i) * 68 + u * 16 + rl] = acc[s][u][i];
    }
    __syncthreads();

    const int rloc = w * 8 + (lane >> 3);      // 0..31
    const int c0 = (lane & 7) * 8;
    f32x4 s0 = {0.f, 0.f, 0.f, 0.f}, s1 = {0.f, 0.f, 0.f, 0.f};
    #pragma unroll
    for (int q = 0; q < 4; ++q) {
      const float* src = fl + q * 2176 + rloc * 68 + c0;
      s0 += *(const f32x4*)src;
      s1 += *(const f32x4*)(src + 4);
    }
    const int gr = row0 + p * 32 + rloc;
    const int gc = col0 + c0;
    const f32x4 bb0 = *(const f32x4*)&bp[gc];
    const f32x4 bb1 = *(const f32x4*)&bp[gc + 4];
    f32x4 o0, o1;
    #pragma unroll
    for (int i = 0; i < 4; ++i) {
      o0[i] = fmaxf(s0[i] + bb0[i], 0.f);
      o1[i] = fmaxf(s1[i] + bb1[i], 0.f);
    }
    float* Hp = H + (size_t)gr * 512 + gc;
    *(f32x4*)Hp = o0;
    *(f32x4*)(Hp + 4) = o1;
    #pragma unroll
    for (int i = 0; i < 4; ++i) {
      if (gc + i < 500) {
        const float v = o0[i], vm = v - 1.0f;
        lmax = fmaxf(lmax, fmaxf(v * v, vm * vm));
      }
      if (gc + 4 + i < 500) {
        const float v = o1[i], vm = v - 1.0f;
        lmax = fmaxf(lmax, fmaxf(v * v, vm * vm));
      }
    }
  }

  #pragma unroll
  for (int off = 32; off; off >>= 1)
    lmax = fmaxf(lmax, __shfl_xor(lmax, off));
  if (lane == 0) red4[w] = lmax;
  __syncthreads();
  if (tid == 0)
    cmaxArr[blockIdx.x] =
        fmaxf(fmaxf(red4[0], red4[1]), fmaxf(red4[2], red4[3]));
}

// ---- prep: job = one 4KB tile; thread = slot -> fully coalesced writes ----
__global__ __launch_bounds__(256) void prep_k(MegaArgs a)
{
  const int sIdx = threadIdx.x;
  const int m = ((sIdx >> 6) << 4) | (sIdx & 15);
  const int g = (sIdx >> 4) & 3;
  for (int job = blockIdx.x; job < 2561; job += gridDim.x) {
    if (job < 2048) {                       // x -> Ablk: (panel, tile)
      const int p = job >> 5, t = job & 31;
      const float* src = a.x + (size_t)(p * 64 + m) * 1024 + t * 32 + g * 8;
      float v[8];
      const f32x4 u0 = *(const f32x4*)src;
      const f32x4 u1 = *(const f32x4*)(src + 4);
      #pragma unroll
      for (int i = 0; i < 4; ++i) { v[i] = u0[i]; v[4 + i] = u1[i]; }
      short* d = a.Ablk + ((size_t)p * 64 + t) * 2048 + sIdx * 8;
      cvt_store16(d, d + 65536, v);         // lo: +32*2048
    } else if (job < 2304) {                // W1 -> B1blk
      const int j = job - 2048;
      const int p = j >> 5, t = j & 31;
      const int n = p * 64 + m;
      float v[8];
      #pragma unroll
      for (int i = 0; i < 8; ++i) {
        const int k = t * 32 + g * 8 + i;
        v[i] = (n < 500) ? a.W1[(size_t)k * 500 + n] : 0.0f;
      }
      short* d = a.B1blk + ((size_t)p * 64 + t) * 2048 + sIdx * 8;
      cvt_store16(d, d + 65536, v);
    } else if (job < 2560) {                // W2/W3 -> B2blk/B3blk
      const int j = (job - 2304) & 127;
      const bool isW3 = (job >= 2432);
      const float* W = isW3 ? a.W3 : a.W2;
      short* Bb = isW3 ? a.B3blk : a.B2blk;
      const int p = j >> 4, t = j & 15;
      const int n = p * 64 + m;
      float v[8];
      #pragma unroll
      for (int i = 0; i < 8; ++i) {
        const int k = t * 32 + g * 8 + i;
        v[i] = (n < 500 && k < 500) ? W[(size_t)k * 500 + n] : 0.0f;
      }
      short* d = Bb + ((size_t)p * 32 + t) * 2048 + sIdx * 8;
      cvt_store16(d, d + 32768, v);         // lo: +16*2048
    } else {                                // bias pad bp[3][512]
      for (int r = 0; r < 6; ++r) {
        const int idx = r * 256 + threadIdx.x;
        const int L = idx >> 9, c = idx & 511;
        const float* src = (L == 0) ? a.b1 : (L == 1) ? a.b2 : a.b3;
        a.bp[idx] = (c < 500) ? src[c] : 0.0f;
      }
    }
  }
}

// ---- soft-topk via Newton on A(t)=400. 1 row/wave, per-row early exit ----
template <bool FINAL>
__global__ __launch_bounds__(256) void sinkhorn_k(
    MegaArgs a, const float* __restrict__ cmaxArr, short* __restrict__ outBlk)
{
  const int w    = threadIdx.x >> 6;
  const int lane = threadIdx.x & 63;
  const int row  = blockIdx.x * 4 + w;

  // global cmax: reduce 512 per-block maxima (2KB, L2-hot)
  const f32x4 cc0 = *(const f32x4*)&cmaxArr[lane * 8];
  const f32x4 cc1 = *(const f32x4*)&cmaxArr[lane * 8 + 4];
  float cmax = fmaxf(fmaxf(fmaxf(cc0[0], cc0[1]), fmaxf(cc0[2], cc0[3])),
                     fmaxf(fmaxf(cc1[0], cc1[1]), fmaxf(cc1[2], cc1[3])));
  #pragma unroll
  for (int off = 32; off; off >>= 1)
    cmax = fmaxf(cmax, __shfl_xor(cmax, off));

  const float s   = (float)a.sparse[0];
  const float inv = 1.0f / (0.1f * cmax);

  const float* Hr = a.H + (size_t)row * 512 + lane * 8;
  const f32x4 u0 = *(const f32x4*)Hr;
  const f32x4 u1 = *(const f32x4*)(Hr + 4);
  float h[8] = {u0[0], u0[1], u0[2], u0[3], u1[0], u1[1], u1[2], u1[3]};
  float R[8];
  #pragma unroll
  for (int j = 0; j < 8; ++j) R[j] = __expf((2.0f * h[j] - 1.0f) * inv);

  const int nval = min(max(500 - lane * 8, 0), 8);

  // Newton: g(t) = A(t) - 400;  A = sum w, w = 1/(1+tR);  A' = -(A - S)/t,
  // S = sum w^2.  t_{n+1} = t + (A-400)*t/(A-S).  Convex g => monotone
  // convergence from the g>=0 side; clamp guards a low first step.
  float t = 1.0f, A = 0.0f;
  for (int it = 0; it < 50; ++it) {
    A = 0.0f;
    float S = 0.0f;
    #pragma unroll
    for (int j = 0; j < 8; ++j) {
      float wv = __builtin_amdgcn_rcpf(fmaf(t, R[j], 1.0f));
      if (j >= nval) wv = 0.0f;
      A += wv;
      S = fmaf(wv, wv, S);
    }
    #pragma unroll
    for (int off = 32; off; off >>= 1) {
      A += __shfl_xor(A, off);
      S += __shfl_xor(S, off);
    }
    if (it == 49) break;
    const float tn = t + (A - 400.0f) * t * __builtin_amdgcn_rcpf(A - S);
    if (__float_as_uint(tn) == __float_as_uint(t)) break;  // bitwise fixed pt
    t = (tn > 0.0f) ? tn : 0.125f * t;
  }

  const float kA = 400.0f / A;
  float mh[8];
  #pragma unroll
  for (int j = 0; j < 8; ++j) {
    const float wv = __builtin_amdgcn_rcpf(fmaf(t, R[j], 1.0f));
    float o = h[j] * (s * (kA * wv) + (1.0f - s));
    if (j >= nval) o = 0.0f;
    mh[j] = o;
  }

  if (!FINAL) {
    short hi[8], lo[8];
    #pragma unroll
    for (int j = 0; j < 8; ++j) {
      const unsigned short hh = f2bf(mh[j]);
      hi[j] = (short)hh;
      lo[j] = (short)f2bf(mh[j] - bf2f(hh));
    }
    const int p = row >> 6, m = row & 63;
    const int tt = lane >> 2, g = lane & 3;
    const int slot = ((m >> 4) << 6) + (g << 4) + (m & 15);
    short* o = outBlk + ((size_t)p * 32 + tt) * 2048 + slot * 8;
    *(uint4*)o           = *(const uint4*)hi;
    *(uint4*)(o + 32768) = *(const uint4*)lo;   // lo tiles: +16*2048
  } else {
    float acc[10];
    #pragma unroll
    for (int o = 0; o < 10; ++o) acc[o] = 0.0f;
    const float* Wr = a.W4 + (size_t)lane * 80;
    #pragma unroll
    for (int j = 0; j < 8; ++j) {
      if (j < nval) {
        #pragma unroll
        for (int o = 0; o < 10; ++o)
          acc[o] = fmaf(mh[j], Wr[j * 10 + o], acc[o]);
      }
    }
    #pragma unroll
    for (int o = 0; o < 10; ++o) {
      #pragma unroll
      for (int off = 32; off; off >>= 1) acc[o] += __shfl_xor(acc[o], off);
    }
    if (lane == 0) {
      #pragma unroll
      for (int o = 0; o < 10; ++o)
        a.out[(size_t)row * 10 + o] = acc[o] + a.b4[o];
    }
  }
}

extern "C" void kernel_launch(void* const* d_in, const int* in_sizes, int n_in,
                              void* d_out, int out_size, void* d_ws, size_t ws_size,
                              hipStream_t stream)
{
  char* ws = (char*)d_ws;

  MegaArgs a;
  a.x  = (const float*)d_in[0];
  a.W1 = (const float*)d_in[1];
  a.b1 = (const float*)d_in[2];
  a.W2 = (const float*)d_in[3];
  a.b2 = (const float*)d_in[4];
  a.W3 = (const float*)d_in[5];
  a.b3 = (const float*)d_in[6];
  a.W4 = (const float*)d_in[7];
  a.b4 = (const float*)d_in[8];
  a.sparse = (const int*)d_in[9];
  a.out = (float*)d_out;

  a.cmaxA = (float*)ws;                                      // [3][512]
  a.bp    = (float*)(ws + 8192);                             // [3][512]
  a.Ablk  = (short*)(ws + 16384);                            // 16MB
  a.B1blk = a.Ablk  + (size_t)64 * 64 * 2048;                // 2MB
  a.B2blk = a.B1blk + (size_t)8 * 64 * 2048;                 // 1MB
  a.B3blk = a.B2blk + (size_t)8 * 32 * 2048;                 // 1MB
  a.H     = (float*)(a.B3blk + (size_t)8 * 32 * 2048);       // 8MB
  a.Hmblk = (short*)(a.H + (size_t)4096 * 512);              // 8MB

  prep_k<<<512, 256, 0, stream>>>(a);
  gemm_k<32><<<512, 256, 0, stream>>>(a.Ablk, a.B1blk, a.bp, a.H, a.cmaxA);
  sinkhorn_k<false><<<1024, 256, 0, stream>>>(a, a.cmaxA, a.Hmblk);
  gemm_k<16><<<512, 256, 0, stream>>>(a.Hmblk, a.B2blk, a.bp + 512, a.H,
                                      a.cmaxA + 512);
  sinkhorn_k<false><<<1024, 256, 0, stream>>>(a, a.cmaxA + 512, a.Hmblk);
  gemm_k<16><<<512, 256, 0, stream>>>(a.Hmblk, a.B3blk, a.bp + 1024, a.H,
                                      a.cmaxA + 1024);
  sinkhorn_k<true><<<1024, 256, 0, stream>>>(a, a.cmaxA + 1024, nullptr);
}

// Round 12
// 90.790 us; speedup vs baseline: 2.0620x; 1.6471x over previous
//
#include <hip/hip_runtime.h>
#include <math.h>

// ---------------------------------------------------------------------------
// NeuralNet_62045097558546 on MI355X (gfx950)
// 3x (GEMM+bias+ReLU+cmax -> soft-topk mask) -> GEMM+bias
// GEMMs: bf16 MFMA split precision, C = Ahi*Bhi + Ahi*Blo + Alo*Bhi as one
// bf16 GEMM over K' = 3K. Physical: compact [hi(NTK)|lo(NTK)] 4KB tiles.
//   A'=[hi|hi|lo]: ta = t<NTK ? t : t-NTK
//   B'=[hi|lo|hi]: tb = t<2NTK ? t : t-2NTK
// FRAGMENT-ORDER BLOCKED LAYOUT: panel p (64 rows) -> tile t (32 k') ->
//   slot s = (m>>4)*64 + g*16 + (m&15) (8 shorts: row m, k-chunk g).
//   Fragment load for sub-tile s16 = ONE contiguous 1KB block per 64 lanes.
// GEMM K-loop: no LDS/barriers/atomics; compile-time 3-stage reg pipeline.
//
// Soft-topk: 50-step 2-anchor Sinkhorn == scalar root of A(t)=400,
// A(t) = sum 1/(1+t*R_i). NEWTON with A' = -(A-S)/t, S = sum w^2.
// r11 lesson: bitwise-equality exit never fires (rcp noise makes the
// ~1-ulp Newton increment oscillate in sign) -> all 50 its ran. Exit on
// |A-400| < 0.01 instead (quadratic convergence reaches it in ~6-9 its;
// mask perturbation ~2.5e-5 rel, invisible vs 4.88e-4 GEMM-dominated absmax).
// ---------------------------------------------------------------------------

typedef __attribute__((ext_vector_type(8))) short short8;
typedef __attribute__((ext_vector_type(4))) float f32x4;

__device__ __forceinline__ unsigned short f2bf(float f) {
  unsigned u = __float_as_uint(f);
  u += 0x7fffu + ((u >> 16) & 1u);
  return (unsigned short)(u >> 16);
}
__device__ __forceinline__ float bf2f(unsigned short s) {
  return __uint_as_float(((unsigned)s) << 16);
}

struct MegaArgs {
  const float *x, *W1, *b1, *W2, *b2, *W3, *b3, *W4, *b4;
  const int* sparse;
  float* out;
  short *Ablk, *B1blk, *B2blk, *B3blk, *Hmblk;
  float *H, *bp, *cmaxA;
};

__device__ __forceinline__ void cvt_store16(short* dstHi, short* dstLo,
                                            const float* v) {
  short hi[8], lo[8];
  #pragma unroll
  for (int i = 0; i < 8; ++i) {
    const unsigned short h = f2bf(v[i]);
    hi[i] = (short)h;
    lo[i] = (short)f2bf(v[i] - bf2f(h));
  }
  *(uint4*)dstHi = *(const uint4*)hi;
  *(uint4*)dstLo = *(const uint4*)lo;
}

#define LDF(t, va, vb)                                                   \
  do {                                                                   \
    const int ta_ = ((t) < NTK) ? (t) : (t) - NTK;                       \
    const int tb_ = ((t) < 2 * NTK) ? (t) : (t) - 2 * NTK;               \
    const short* Ag_ = Abase + (size_t)ta_ * 2048;                       \
    const short* Bg_ = Bbase + (size_t)tb_ * 2048;                       \
    va[0] = *(const short8*)(Ag_);                                       \
    va[1] = *(const short8*)(Ag_ + 512);                                 \
    va[2] = *(const short8*)(Ag_ + 1024);                                \
    va[3] = *(const short8*)(Ag_ + 1536);                                \
    vb[0] = *(const short8*)(Bg_);                                       \
    vb[1] = *(const short8*)(Bg_ + 512);                                 \
    vb[2] = *(const short8*)(Bg_ + 1024);                                \
    vb[3] = *(const short8*)(Bg_ + 1536);                                \
  } while (0)

#define CMP(va, vb)                                                      \
  do {                                                                   \
    _Pragma("unroll")                                                    \
    for (int s_ = 0; s_ < 4; ++s_)                                       \
      _Pragma("unroll")                                                  \
      for (int u_ = 0; u_ < 4; ++u_)                                     \
        acc[s_][u_] = __builtin_amdgcn_mfma_f32_16x16x32_bf16(           \
            va[s_], vb[u_], acc[s_][u_], 0, 0, 0);                       \
  } while (0)

// ---- GEMM kernel: one 64x64 tile/block, per-wave split-K, reg pipeline ----
template <int NTK>
__global__ __launch_bounds__(256, 2) void gemm_k(
    const short* __restrict__ Ablk, const short* __restrict__ Bblk,
    const float* __restrict__ bp, float* __restrict__ H,
    float* __restrict__ cmaxArr)
{
  __shared__ __align__(16) float fl[8704];   // epilogue: 4 x [32][68]
  __shared__ float red4[4];

  const int tid  = threadIdx.x;
  const int lane = tid & 63, w = tid >> 6;
  const int rg = lane >> 4, rl = lane & 15;

  // by fast: XCD (blockIdx%8) keeps its 8 A row-panels L2-resident.
  const int by = blockIdx.x & 63, bx = blockIdx.x >> 6;
  const int row0 = by * 64, col0 = bx * 64;

  const short* Abase = Ablk + (size_t)by * (2 * NTK) * 2048 + lane * 8;
  const short* Bbase = Bblk + (size_t)bx * (2 * NTK) * 2048 + lane * 8;

  constexpr int nt = (3 * NTK) >> 2;   // 24 (K=1024) / 12 (K=512)
  const int t0 = w * nt;

  f32x4 acc[4][4];
  #pragma unroll
  for (int s = 0; s < 4; ++s)
    #pragma unroll
    for (int u = 0; u < 4; ++u)
      acc[s][u] = (f32x4){0.f, 0.f, 0.f, 0.f};

  short8 A0[4], B0[4], A1[4], B1[4], A2[4], B2[4];
  LDF(t0 + 0, A0, B0);
  LDF(t0 + 1, A1, B1);
  LDF(t0 + 2, A2, B2);
  #pragma unroll
  for (int i = 0; i < nt; i += 3) {
    CMP(A0, B0);
    if (i + 3 < nt) LDF(t0 + i + 3, A0, B0);
    CMP(A1, B1);
    if (i + 4 < nt) LDF(t0 + i + 4, A1, B1);
    CMP(A2, B2);
    if (i + 5 < nt) LDF(t0 + i + 5, A2, B2);
  }

  // ---- epilogue: 2-pass cross-wave split-K reduce + bias + relu + cmax ----
  float lmax = 0.0f;
  #pragma unroll
  for (int p = 0; p < 2; ++p) {
    if (p == 1) __syncthreads();
    #pragma unroll
    for (int sp = 0; sp < 2; ++sp) {
      const int s = p * 2 + sp;
      #pragma unroll
      for (int u = 0; u < 4; ++u)
        #pragma unroll
        for (int i = 0; i < 4; ++i)
          fl[w * 2176 + (sp * 16 + rg * 4 + i) * 68 + u * 16 + rl] = acc[s][u][i];
    }
    __syncthreads();

    const int rloc = w * 8 + (lane >> 3);      // 0..31
    const int c0 = (lane & 7) * 8;
    f32x4 s0 = {0.f, 0.f, 0.f, 0.f}, s1 = {0.f, 0.f, 0.f, 0.f};
    #pragma unroll
    for (int q = 0; q < 4; ++q) {
      const float* src = fl + q * 2176 + rloc * 68 + c0;
      s0 += *(const f32x4*)src;
      s1 += *(const f32x4*)(src + 4);
    }
    const int gr = row0 + p * 32 + rloc;
    const int gc = col0 + c0;
    const f32x4 bb0 = *(const f32x4*)&bp[gc];
    const f32x4 bb1 = *(const f32x4*)&bp[gc + 4];
    f32x4 o0, o1;
    #pragma unroll
    for (int i = 0; i < 4; ++i) {
      o0[i] = fmaxf(s0[i] + bb0[i], 0.f);
      o1[i] = fmaxf(s1[i] + bb1[i], 0.f);
    }
    float* Hp = H + (size_t)gr * 512 + gc;
    *(f32x4*)Hp = o0;
    *(f32x4*)(Hp + 4) = o1;
    #pragma unroll
    for (int i = 0; i < 4; ++i) {
      if (gc + i < 500) {
        const float v = o0[i], vm = v - 1.0f;
        lmax = fmaxf(lmax, fmaxf(v * v, vm * vm));
      }
      if (gc + 4 + i < 500) {
        const float v = o1[i], vm = v - 1.0f;
        lmax = fmaxf(lmax, fmaxf(v * v, vm * vm));
      }
    }
  }

  #pragma unroll
  for (int off = 32; off; off >>= 1)
    lmax = fmaxf(lmax, __shfl_xor(lmax, off));
  if (lane == 0) red4[w] = lmax;
  __syncthreads();
  if (tid == 0)
    cmaxArr[blockIdx.x] =
        fmaxf(fmaxf(red4[0], red4[1]), fmaxf(red4[2], red4[3]));
}

// ---- prep: job = one 4KB tile; thread = slot -> fully coalesced writes ----
__global__ __launch_bounds__(256) void prep_k(MegaArgs a)
{
  const int sIdx = threadIdx.x;
  const int m = ((sIdx >> 6) << 4) | (sIdx & 15);
  const int g = (sIdx >> 4) & 3;
  for (int job = blockIdx.x; job < 2561; job += gridDim.x) {
    if (job < 2048) {                       // x -> Ablk: (panel, tile)
      const int p = job >> 5, t = job & 31;
      const float* src = a.x + (size_t)(p * 64 + m) * 1024 + t * 32 + g * 8;
      float v[8];
      const f32x4 u0 = *(const f32x4*)src;
      const f32x4 u1 = *(const f32x4*)(src + 4);
      #pragma unroll
      for (int i = 0; i < 4; ++i) { v[i] = u0[i]; v[4 + i] = u1[i]; }
      short* d = a.Ablk + ((size_t)p * 64 + t) * 2048 + sIdx * 8;
      cvt_store16(d, d + 65536, v);         // lo: +32*2048
    } else if (job < 2304) {                // W1 -> B1blk
      const int j = job - 2048;
      const int p = j >> 5, t = j & 31;
      const int n = p * 64 + m;
      float v[8];
      #pragma unroll
      for (int i = 0; i < 8; ++i) {
        const int k = t * 32 + g * 8 + i;
        v[i] = (n < 500) ? a.W1[(size_t)k * 500 + n] : 0.0f;
      }
      short* d = a.B1blk + ((size_t)p * 64 + t) * 2048 + sIdx * 8;
      cvt_store16(d, d + 65536, v);
    } else if (job < 2560) {                // W2/W3 -> B2blk/B3blk
      const int j = (job - 2304) & 127;
      const bool isW3 = (job >= 2432);
      const float* W = isW3 ? a.W3 : a.W2;
      short* Bb = isW3 ? a.B3blk : a.B2blk;
      const int p = j >> 4, t = j & 15;
      const int n = p * 64 + m;
      float v[8];
      #pragma unroll
      for (int i = 0; i < 8; ++i) {
        const int k = t * 32 + g * 8 + i;
        v[i] = (n < 500 && k < 500) ? W[(size_t)k * 500 + n] : 0.0f;
      }
      short* d = Bb + ((size_t)p * 32 + t) * 2048 + sIdx * 8;
      cvt_store16(d, d + 32768, v);         // lo: +16*2048
    } else {                                // bias pad bp[3][512]
      for (int r = 0; r < 6; ++r) {
        const int idx = r * 256 + threadIdx.x;
        const int L = idx >> 9, c = idx & 511;
        const float* src = (L == 0) ? a.b1 : (L == 1) ? a.b2 : a.b3;
        a.bp[idx] = (c < 500) ? src[c] : 0.0f;
      }
    }
  }
}

// ---- soft-topk via Newton on A(t)=400. 1 row/wave, tolerance early exit ----
template <bool FINAL>
__global__ __launch_bounds__(256) void sinkhorn_k(
    MegaArgs a, const float* __restrict__ cmaxArr, short* __restrict__ outBlk)
{
  const int w    = threadIdx.x >> 6;
  const int lane = threadIdx.x & 63;
  const int row  = blockIdx.x * 4 + w;

  // global cmax: reduce 512 per-block maxima (2KB, L2-hot)
  const f32x4 cc0 = *(const f32x4*)&cmaxArr[lane * 8];
  const f32x4 cc1 = *(const f32x4*)&cmaxArr[lane * 8 + 4];
  float cmax = fmaxf(fmaxf(fmaxf(cc0[0], cc0[1]), fmaxf(cc0[2], cc0[3])),
                     fmaxf(fmaxf(cc1[0], cc1[1]), fmaxf(cc1[2], cc1[3])));
  #pragma unroll
  for (int off = 32; off; off >>= 1)
    cmax = fmaxf(cmax, __shfl_xor(cmax, off));

  const float s   = (float)a.sparse[0];
  const float inv = 1.0f / (0.1f * cmax);

  const float* Hr = a.H + (size_t)row * 512 + lane * 8;
  const f32x4 u0 = *(const f32x4*)Hr;
  const f32x4 u1 = *(const f32x4*)(Hr + 4);
  float h[8] = {u0[0], u0[1], u0[2], u0[3], u1[0], u1[1], u1[2], u1[3]};
  float R[8];
  #pragma unroll
  for (int j = 0; j < 8; ++j) R[j] = __expf((2.0f * h[j] - 1.0f) * inv);

  const int nval = min(max(500 - lane * 8, 0), 8);

  // Newton: g(t) = A(t) - 400;  A = sum w, w = 1/(1+tR);  A' = -(A - S)/t,
  // S = sum w^2.  t_{n+1} = t + (A-400)*t/(A-S).  Exit on |A-400| < 0.01
  // (bitwise exit oscillates under rcp noise -> ran all 50 its in r11).
  float t = 1.0f, A = 0.0f;
  for (int it = 0; it < 50; ++it) {
    A = 0.0f;
    float S = 0.0f;
    #pragma unroll
    for (int j = 0; j < 8; ++j) {
      float wv = __builtin_amdgcn_rcpf(fmaf(t, R[j], 1.0f));
      if (j >= nval) wv = 0.0f;
      A += wv;
      S = fmaf(wv, wv, S);
    }
    #pragma unroll
    for (int off = 32; off; off >>= 1) {
      A += __shfl_xor(A, off);
      S += __shfl_xor(S, off);
    }
    if (fabsf(A - 400.0f) < 0.01f || it == 49) break;  // converged (tol)
    const float tn = t + (A - 400.0f) * t * __builtin_amdgcn_rcpf(A - S);
    if (__float_as_uint(tn) == __float_as_uint(t)) break;  // bitwise backstop
    t = (tn > 0.0f) ? tn : 0.125f * t;
  }

  const float kA = 400.0f / A;
  float mh[8];
  #pragma unroll
  for (int j = 0; j < 8; ++j) {
    const float wv = __builtin_amdgcn_rcpf(fmaf(t, R[j], 1.0f));
    float o = h[j] * (s * (kA * wv) + (1.0f - s));
    if (j >= nval) o = 0.0f;
    mh[j] = o;
  }

  if (!FINAL) {
    short hi[8], lo[8];
    #pragma unroll
    for (int j = 0; j < 8; ++j) {
      const unsigned short hh = f2bf(mh[j]);
      hi[j] = (short)hh;
      lo[j] = (short)f2bf(mh[j] - bf2f(hh));
    }
    const int p = row >> 6, m = row & 63;
    const int tt = lane >> 2, g = lane & 3;
    const int slot = ((m >> 4) << 6) + (g << 4) + (m & 15);
    short* o = outBlk + ((size_t)p * 32 + tt) * 2048 + slot * 8;
    *(uint4*)o           = *(const uint4*)hi;
    *(uint4*)(o + 32768) = *(const uint4*)lo;   // lo tiles: +16*2048
  } else {
    float acc[10];
    #pragma unroll
    for (int o = 0; o < 10; ++o) acc[o] = 0.0f;
    const float* Wr = a.W4 + (size_t)lane * 80;
    #pragma unroll
    for (int j = 0; j < 8; ++j) {
      if (j < nval) {
        #pragma unroll
        for (int o = 0; o < 10; ++o)
          acc[o] = fmaf(mh[j], Wr[j * 10 + o], acc[o]);
      }
    }
    #pragma unroll
    for (int o = 0; o < 10; ++o) {
      #pragma unroll
      for (int off = 32; off; off >>= 1) acc[o] += __shfl_xor(acc[o], off);
    }
    if (lane == 0) {
      #pragma unroll
      for (int o = 0; o < 10; ++o)
        a.out[(size_t)row * 10 + o] = acc[o] + a.b4[o];
    }
  }
}

extern "C" void kernel_launch(void* const* d_in, const int* in_sizes, int n_in,
                              void* d_out, int out_size, void* d_ws, size_t ws_size,
                              hipStream_t stream)
{
  char* ws = (char*)d_ws;

  MegaArgs a;
  a.x  = (const float*)d_in[0];
  a.W1 = (const float*)d_in[1];
  a.b1 = (const float*)d_in[2];
  a.W2 = (const float*)d_in[3];
  a.b2 = (const float*)d_in[4];
  a.W3 = (const float*)d_in[5];
  a.b3 = (const float*)d_in[6];
  a.W4 = (const float*)d_in[7];
  a.b4 = (const float*)d_in[8];
  a.sparse = (const int*)d_in[9];
  a.out = (float*)d_out;

  a.cmaxA = (float*)ws;                                      // [3][512]
  a.bp    = (float*)(ws + 8192);                             // [3][512]
  a.Ablk  = (short*)(ws + 16384);                            // 16MB
  a.B1blk = a.Ablk  + (size_t)64 * 64 * 2048;                // 2MB
  a.B2blk = a.B1blk + (size_t)8 * 64 * 2048;                 // 1MB
  a.B3blk = a.B2blk + (size_t)8 * 32 * 2048;                 // 1MB
  a.H     = (float*)(a.B3blk + (size_t)8 * 32 * 2048);       // 8MB
  a.Hmblk = (short*)(a.H + (size_t)4096 * 512);              // 8MB

  prep_k<<<512, 256, 0, stream>>>(a);
  gemm_k<32><<<512, 256, 0, stream>>>(a.Ablk, a.B1blk, a.bp, a.H, a.cmaxA);
  sinkhorn_k<false><<<1024, 256, 0, stream>>>(a, a.cmaxA, a.Hmblk);
  gemm_k<16><<<512, 256, 0, stream>>>(a.Hmblk, a.B2blk, a.bp + 512, a.H,
                                      a.cmaxA + 512);
  sinkhorn_k<false><<<1024, 256, 0, stream>>>(a, a.cmaxA + 512, a.Hmblk);
  gemm_k<16><<<512, 256, 0, stream>>>(a.Hmblk, a.B3blk, a.bp + 1024, a.H,
                                      a.cmaxA + 1024);
  sinkhorn_k<true><<<1024, 256, 0, stream>>>(a, a.cmaxA + 1024, nullptr);
}

// Round 14
// 90.523 us; speedup vs baseline: 2.0681x; 1.0029x over previous
//
#include <hip/hip_runtime.h>
#include <math.h>

// ---------------------------------------------------------------------------
// NeuralNet_62045097558546 on MI355X (gfx950)
// 3x (GEMM+bias+ReLU+cmax -> soft-topk mask) -> GEMM+bias
// GEMMs: bf16 MFMA split precision, C = Ahi*Bhi + Ahi*Blo + Alo*Bhi as one
// bf16 GEMM over K' = 3K. Physical: compact [hi(NTK)|lo(NTK)] 4KB tiles.
//   A'=[hi|hi|lo]: ta = t<NTK ? t : t-NTK
//   B'=[hi|lo|hi]: tb = t<2NTK ? t : t-2NTK
// FRAGMENT-ORDER BLOCKED LAYOUT: panel p (64 rows) -> tile t (32 k') ->
//   slot s = (m>>4)*64 + g*16 + (m&15) (8 shorts: row m, k-chunk g).
//   Fragment load for sub-tile s16 = ONE contiguous 1KB block per 64 lanes.
// GEMM K-loop: no LDS/barriers/atomics; compile-time 3-stage reg pipeline.
//
// Soft-topk: 50-step 2-anchor Sinkhorn == scalar root of A(t)=400,
// A(t) = sum 1/(1+t*R_i), strictly decreasing (A(0+)=500, A(inf)=0).
// SAFEGUARDED log-Newton: u=ln t in bracket [u_lo,u_hi] (init +-40);
// Newton du=(A-400)/(A-S) (S=sum w^2, dg/du=-(A-S)); step leaving the
// bracket -> bisect. r13 lesson: UNSAFEGUARDED log-Newton overshoot-
// oscillates (far regime du~(A-400)/A clamped +-16 ping-pongs between
// regimes; rows exited at it=49 with garbage (t,A) -> absmax 0.135).
// Bracketing is globally convergent; quadratic near root; exit |A-400|<0.01
// (validated r12).
// ---------------------------------------------------------------------------

typedef __attribute__((ext_vector_type(8))) short short8;
typedef __attribute__((ext_vector_type(4))) float f32x4;

__device__ __forceinline__ unsigned short f2bf(float f) {
  unsigned u = __float_as_uint(f);
  u += 0x7fffu + ((u >> 16) & 1u);
  return (unsigned short)(u >> 16);
}
__device__ __forceinline__ float bf2f(unsigned short s) {
  return __uint_as_float(((unsigned)s) << 16);
}

struct MegaArgs {
  const float *x, *W1, *b1, *W2, *b2, *W3, *b3, *W4, *b4;
  const int* sparse;
  float* out;
  short *Ablk, *B1blk, *B2blk, *B3blk, *Hmblk;
  float *H, *bp, *cmaxA;
};

__device__ __forceinline__ void cvt_store16(short* dstHi, short* dstLo,
                                            const float* v) {
  short hi[8], lo[8];
  #pragma unroll
  for (int i = 0; i < 8; ++i) {
    const unsigned short h = f2bf(v[i]);
    hi[i] = (short)h;
    lo[i] = (short)f2bf(v[i] - bf2f(h));
  }
  *(uint4*)dstHi = *(const uint4*)hi;
  *(uint4*)dstLo = *(const uint4*)lo;
}

#define LDF(t, va, vb)                                                   \
  do {                                                                   \
    const int ta_ = ((t) < NTK) ? (t) : (t) - NTK;                       \
    const int tb_ = ((t) < 2 * NTK) ? (t) : (t) - 2 * NTK;               \
    const short* Ag_ = Abase + (size_t)ta_ * 2048;                       \
    const short* Bg_ = Bbase + (size_t)tb_ * 2048;                       \
    va[0] = *(const short8*)(Ag_);                                       \
    va[1] = *(const short8*)(Ag_ + 512);                                 \
    va[2] = *(const short8*)(Ag_ + 1024);                                \
    va[3] = *(const short8*)(Ag_ + 1536);                                \
    vb[0] = *(const short8*)(Bg_);                                       \
    vb[1] = *(const short8*)(Bg_ + 512);                                 \
    vb[2] = *(const short8*)(Bg_ + 1024);                                \
    vb[3] = *(const short8*)(Bg_ + 1536);                                \
  } while (0)

#define CMP(va, vb)                                                      \
  do {                                                                   \
    _Pragma("unroll")                                                    \
    for (int s_ = 0; s_ < 4; ++s_)                                       \
      _Pragma("unroll")                                                  \
      for (int u_ = 0; u_ < 4; ++u_)                                     \
        acc[s_][u_] = __builtin_amdgcn_mfma_f32_16x16x32_bf16(           \
            va[s_], vb[u_], acc[s_][u_], 0, 0, 0);                       \
  } while (0)

// ---- GEMM kernel: one 64x64 tile/block, per-wave split-K, reg pipeline ----
template <int NTK>
__global__ __launch_bounds__(256, 2) void gemm_k(
    const short* __restrict__ Ablk, const short* __restrict__ Bblk,
    const float* __restrict__ bp, float* __restrict__ H,
    float* __restrict__ cmaxArr)
{
  __shared__ __align__(16) float fl[8704];   // epilogue: 4 x [32][68]
  __shared__ float red4[4];

  const int tid  = threadIdx.x;
  const int lane = tid & 63, w = tid >> 6;
  const int rg = lane >> 4, rl = lane & 15;

  // by fast: XCD (blockIdx%8) keeps its 8 A row-panels L2-resident.
  const int by = blockIdx.x & 63, bx = blockIdx.x >> 6;
  const int row0 = by * 64, col0 = bx * 64;

  const short* Abase = Ablk + (size_t)by * (2 * NTK) * 2048 + lane * 8;
  const short* Bbase = Bblk + (size_t)bx * (2 * NTK) * 2048 + lane * 8;

  constexpr int nt = (3 * NTK) >> 2;   // 24 (K=1024) / 12 (K=512)
  const int t0 = w * nt;

  f32x4 acc[4][4];
  #pragma unroll
  for (int s = 0; s < 4; ++s)
    #pragma unroll
    for (int u = 0; u < 4; ++u)
      acc[s][u] = (f32x4){0.f, 0.f, 0.f, 0.f};

  short8 A0[4], B0[4], A1[4], B1[4], A2[4], B2[4];
  LDF(t0 + 0, A0, B0);
  LDF(t0 + 1, A1, B1);
  LDF(t0 + 2, A2, B2);
  #pragma unroll
  for (int i = 0; i < nt; i += 3) {
    CMP(A0, B0);
    if (i + 3 < nt) LDF(t0 + i + 3, A0, B0);
    CMP(A1, B1);
    if (i + 4 < nt) LDF(t0 + i + 4, A1, B1);
    CMP(A2, B2);
    if (i + 5 < nt) LDF(t0 + i + 5, A2, B2);
  }

  // ---- epilogue: 2-pass cross-wave split-K reduce + bias + relu + cmax ----
  float lmax = 0.0f;
  #pragma unroll
  for (int p = 0; p < 2; ++p) {
    if (p == 1) __syncthreads();
    #pragma unroll
    for (int sp = 0; sp < 2; ++sp) {
      const int s = p * 2 + sp;
      #pragma unroll
      for (int u = 0; u < 4; ++u)
        #pragma unroll
        for (int i = 0; i < 4; ++i)
          fl[w * 2176 + (sp * 16 + rg * 4 + i) * 68 + u * 16 + rl] = acc[s][u][i];
    }
    __syncthreads();

    const int rloc = w * 8 + (lane >> 3);      // 0..31
    const int c0 = (lane & 7) * 8;
    f32x4 s0 = {0.f, 0.f, 0.f, 0.f}, s1 = {0.f, 0.f, 0.f, 0.f};
    #pragma unroll
    for (int q = 0; q < 4; ++q) {
      const float* src = fl + q * 2176 + rloc * 68 + c0;
      s0 += *(const f32x4*)src;
      s1 += *(const f32x4*)(src + 4);
    }
    const int gr = row0 + p * 32 + rloc;
    const int gc = col0 + c0;
    const f32x4 bb0 = *(const f32x4*)&bp[gc];
    const f32x4 bb1 = *(const f32x4*)&bp[gc + 4];
    f32x4 o0, o1;
    #pragma unroll
    for (int i = 0; i < 4; ++i) {
      o0[i] = fmaxf(s0[i] + bb0[i], 0.f);
      o1[i] = fmaxf(s1[i] + bb1[i], 0.f);
    }
    float* Hp = H + (size_t)gr * 512 + gc;
    *(f32x4*)Hp = o0;
    *(f32x4*)(Hp + 4) = o1;
    #pragma unroll
    for (int i = 0; i < 4; ++i) {
      if (gc + i < 500) {
        const float v = o0[i], vm = v - 1.0f;
        lmax = fmaxf(lmax, fmaxf(v * v, vm * vm));
      }
      if (gc + 4 + i < 500) {
        const float v = o1[i], vm = v - 1.0f;
        lmax = fmaxf(lmax, fmaxf(v * v, vm * vm));
      }
    }
  }

  #pragma unroll
  for (int off = 32; off; off >>= 1)
    lmax = fmaxf(lmax, __shfl_xor(lmax, off));
  if (lane == 0) red4[w] = lmax;
  __syncthreads();
  if (tid == 0)
    cmaxArr[blockIdx.x] =
        fmaxf(fmaxf(red4[0], red4[1]), fmaxf(red4[2], red4[3]));
}

// ---- prep: job = one 4KB tile; thread = slot -> fully coalesced writes ----
__global__ __launch_bounds__(256) void prep_k(MegaArgs a)
{
  const int sIdx = threadIdx.x;
  const int m = ((sIdx >> 6) << 4) | (sIdx & 15);
  const int g = (sIdx >> 4) & 3;
  for (int job = blockIdx.x; job < 2561; job += gridDim.x) {
    if (job < 2048) {                       // x -> Ablk: (panel, tile)
      const int p = job >> 5, t = job & 31;
      const float* src = a.x + (size_t)(p * 64 + m) * 1024 + t * 32 + g * 8;
      float v[8];
      const f32x4 u0 = *(const f32x4*)src;
      const f32x4 u1 = *(const f32x4*)(src + 4);
      #pragma unroll
      for (int i = 0; i < 4; ++i) { v[i] = u0[i]; v[4 + i] = u1[i]; }
      short* d = a.Ablk + ((size_t)p * 64 + t) * 2048 + sIdx * 8;
      cvt_store16(d, d + 65536, v);         // lo: +32*2048
    } else if (job < 2304) {                // W1 -> B1blk
      const int j = job - 2048;
      const int p = j >> 5, t = j & 31;
      const int n = p * 64 + m;
      float v[8];
      #pragma unroll
      for (int i = 0; i < 8; ++i) {
        const int k = t * 32 + g * 8 + i;
        v[i] = (n < 500) ? a.W1[(size_t)k * 500 + n] : 0.0f;
      }
      short* d = a.B1blk + ((size_t)p * 64 + t) * 2048 + sIdx * 8;
      cvt_store16(d, d + 65536, v);
    } else if (job < 2560) {                // W2/W3 -> B2blk/B3blk
      const int j = (job - 2304) & 127;
      const bool isW3 = (job >= 2432);
      const float* W = isW3 ? a.W3 : a.W2;
      short* Bb = isW3 ? a.B3blk : a.B2blk;
      const int p = j >> 4, t = j & 15;
      const int n = p * 64 + m;
      float v[8];
      #pragma unroll
      for (int i = 0; i < 8; ++i) {
        const int k = t * 32 + g * 8 + i;
        v[i] = (n < 500 && k < 500) ? W[(size_t)k * 500 + n] : 0.0f;
      }
      short* d = Bb + ((size_t)p * 32 + t) * 2048 + sIdx * 8;
      cvt_store16(d, d + 32768, v);         // lo: +16*2048
    } else {                                // bias pad bp[3][512]
      for (int r = 0; r < 6; ++r) {
        const int idx = r * 256 + threadIdx.x;
        const int L = idx >> 9, c = idx & 511;
        const float* src = (L == 0) ? a.b1 : (L == 1) ? a.b2 : a.b3;
        a.bp[idx] = (c < 500) ? src[c] : 0.0f;
      }
    }
  }
}

// ---- soft-topk via SAFEGUARDED log-Newton on A(t)=400. 1 row/wave ----
template <bool FINAL>
__global__ __launch_bounds__(256) void sinkhorn_k(
    MegaArgs a, const float* __restrict__ cmaxArr, short* __restrict__ outBlk)
{
  const int w    = threadIdx.x >> 6;
  const int lane = threadIdx.x & 63;
  const int row  = blockIdx.x * 4 + w;

  // global cmax: reduce 512 per-block maxima (2KB, L2-hot)
  const f32x4 cc0 = *(const f32x4*)&cmaxArr[lane * 8];
  const f32x4 cc1 = *(const f32x4*)&cmaxArr[lane * 8 + 4];
  float cmax = fmaxf(fmaxf(fmaxf(cc0[0], cc0[1]), fmaxf(cc0[2], cc0[3])),
                     fmaxf(fmaxf(cc1[0], cc1[1]), fmaxf(cc1[2], cc1[3])));
  #pragma unroll
  for (int off = 32; off; off >>= 1)
    cmax = fmaxf(cmax, __shfl_xor(cmax, off));

  const float s   = (float)a.sparse[0];
  const float inv = 1.0f / (0.1f * cmax);

  const float* Hr = a.H + (size_t)row * 512 + lane * 8;
  const f32x4 u0 = *(const f32x4*)Hr;
  const f32x4 u1 = *(const f32x4*)(Hr + 4);
  float h[8] = {u0[0], u0[1], u0[2], u0[3], u1[0], u1[1], u1[2], u1[3]};
  float R[8];
  #pragma unroll
  for (int j = 0; j < 8; ++j) R[j] = __expf((2.0f * h[j] - 1.0f) * inv);

  const int nval = min(max(500 - lane * 8, 0), 8);

  // Safeguarded log-Newton on g(u) = A(e^u) - 400 (g decreasing in u):
  //   bracket: g(u_lo) > 0, g(u_hi) < 0, init +-40 (covers any root here);
  //   Newton du = (A-400)/(A-S); if u+du leaves (u_lo,u_hi) -> bisect.
  //   NaN/Inf du also routes to bisect. Exit |A-400| < 0.01.
  float u_lo = -40.0f, u_hi = 40.0f;
  float uu = 0.0f, t = 1.0f, A = 0.0f;
  for (int it = 0; it < 50; ++it) {
    A = 0.0f;
    float S = 0.0f;
    #pragma unroll
    for (int j = 0; j < 8; ++j) {
      float wv = __builtin_amdgcn_rcpf(fmaf(t, R[j], 1.0f));
      if (j >= nval) wv = 0.0f;
      A += wv;
      S = fmaf(wv, wv, S);
    }
    #pragma unroll
    for (int off = 32; off; off >>= 1) {
      A += __shfl_xor(A, off);
      S += __shfl_xor(S, off);
    }
    if (fabsf(A - 400.0f) < 0.01f || it == 49) break;  // converged (tol)
    if (A > 400.0f) u_lo = uu; else u_hi = uu;
    const float du = (A - 400.0f) * __builtin_amdgcn_rcpf(A - S);
    float un = uu + du;
    if (!(un > u_lo && un < u_hi)) un = 0.5f * (u_lo + u_hi);  // bisect
    uu = un;
    t = __expf(uu);
  }

  const float kA = 400.0f / A;
  float mh[8];
  #pragma unroll
  for (int j = 0; j < 8; ++j) {
    const float wv = __builtin_amdgcn_rcpf(fmaf(t, R[j], 1.0f));
    float o = h[j] * (s * (kA * wv) + (1.0f - s));
    if (j >= nval) o = 0.0f;
    mh[j] = o;
  }

  if (!FINAL) {
    short hi[8], lo[8];
    #pragma unroll
    for (int j = 0; j < 8; ++j) {
      const unsigned short hh = f2bf(mh[j]);
      hi[j] = (short)hh;
      lo[j] = (short)f2bf(mh[j] - bf2f(hh));
    }
    const int p = row >> 6, m = row & 63;
    const int tt = lane >> 2, g = lane & 3;
    const int slot = ((m >> 4) << 6) + (g << 4) + (m & 15);
    short* o = outBlk + ((size_t)p * 32 + tt) * 2048 + slot * 8;
    *(uint4*)o           = *(const uint4*)hi;
    *(uint4*)(o + 32768) = *(const uint4*)lo;   // lo tiles: +16*2048
  } else {
    float acc[10];
    #pragma unroll
    for (int o = 0; o < 10; ++o) acc[o] = 0.0f;
    const float* Wr = a.W4 + (size_t)lane * 80;
    #pragma unroll
    for (int j = 0; j < 8; ++j) {
      if (j < nval) {
        #pragma unroll
        for (int o = 0; o < 10; ++o)
          acc[o] = fmaf(mh[j], Wr[j * 10 + o], acc[o]);
      }
    }
    #pragma unroll
    for (int o = 0; o < 10; ++o) {
      #pragma unroll
      for (int off = 32; off; off >>= 1) acc[o] += __shfl_xor(acc[o], off);
    }
    if (lane == 0) {
      #pragma unroll
      for (int o = 0; o < 10; ++o)
        a.out[(size_t)row * 10 + o] = acc[o] + a.b4[o];
    }
  }
}

extern "C" void kernel_launch(void* const* d_in, const int* in_sizes, int n_in,
                              void* d_out, int out_size, void* d_ws, size_t ws_size,
                              hipStream_t stream)
{
  char* ws = (char*)d_ws;

  MegaArgs a;
  a.x  = (const float*)d_in[0];
  a.W1 = (const float*)d_in[1];
  a.b1 = (const float*)d_in[2];
  a.W2 = (const float*)d_in[3];
  a.b2 = (const float*)d_in[4];
  a.W3 = (const float*)d_in[5];
  a.b3 = (const float*)d_in[6];
  a.W4 = (const float*)d_in[7];
  a.b4 = (const float*)d_in[8];
  a.sparse = (const int*)d_in[9];
  a.out = (float*)d_out;

  a.cmaxA = (float*)ws;                                      // [3][512]
  a.bp    = (float*)(ws + 8192);                             // [3][512]
  a.Ablk  = (short*)(ws + 16384);                            // 16MB
  a.B1blk = a.Ablk  + (size_t)64 * 64 * 2048;                // 2MB
  a.B2blk = a.B1blk + (size_t)8 * 64 * 2048;                 // 1MB
  a.B3blk = a.B2blk + (size_t)8 * 32 * 2048;                 // 1MB
  a.H     = (float*)(a.B3blk + (size_t)8 * 32 * 2048);       // 8MB
  a.Hmblk = (short*)(a.H + (size_t)4096 * 512);              // 8MB

  prep_k<<<512, 256, 0, stream>>>(a);
  gemm_k<32><<<512, 256, 0, stream>>>(a.Ablk, a.B1blk, a.bp, a.H, a.cmaxA);
  sinkhorn_k<false><<<1024, 256, 0, stream>>>(a, a.cmaxA, a.Hmblk);
  gemm_k<16><<<512, 256, 0, stream>>>(a.Hmblk, a.B2blk, a.bp + 512, a.H,
                                      a.cmaxA + 512);
  sinkhorn_k<false><<<1024, 256, 0, stream>>>(a, a.cmaxA + 512, a.Hmblk);
  gemm_k<16><<<512, 256, 0, stream>>>(a.Hmblk, a.B3blk, a.bp + 1024, a.H,
                                      a.cmaxA + 1024);
  sinkhorn_k<true><<<1024, 256, 0, stream>>>(a, a.cmaxA + 1024, nullptr);
}